// Round 1
// baseline (464.996 us; speedup 1.0000x reference)
//
#include <hip/hip_runtime.h>
#include <hip/hip_bf16.h>
#include <math.h>

#define C_IN   128
#define C_HID  32
#define N_HEAD 4
#define NSEQ   256
#define LN_EPS 1e-5f

// ws layout (floats):
//   q_buf [I][H][J][32] : 8388608
//   k_buf               : 8388608
//   v_buf               : 8388608
//   g_buf               : 8388608   (attn overwrites with o*g each call)
//   nb_t  [H][k][q]     : 262144
// total = 135,266,304 bytes

// ---------------------------------------------------------------------------
// Kernel 1: LayerNorm + projections (q,k,v,g) + pair-bias nb
// grid 1024 (64 positions each), block 256
// ---------------------------------------------------------------------------
__global__ __launch_bounds__(256) void proj_kernel(
    const float* __restrict__ act, const float* __restrict__ ln_w,
    const float* __restrict__ ln_b, const float* __restrict__ w2d,
    const float* __restrict__ wq, const float* __restrict__ wk,
    const float* __restrict__ wv, const float* __restrict__ wg,
    const float* __restrict__ bg,
    float* __restrict__ q_buf, float* __restrict__ k_buf,
    float* __restrict__ v_buf, float* __restrict__ g_buf,
    float* __restrict__ nb_t)
{
    __shared__ float act_s[64][129];   // x tile, pitch 129 -> conflict-free
    __shared__ float w_s[128][64];     // weight chunk (64 output cols)
    __shared__ float psum[4][64], psq[4][64];
    __shared__ float mu_s[64], rs_s[64];
    __shared__ float lnw_s[C_IN], lnb_s[C_IN];

    const int tid   = threadIdx.x;
    const int pbase = blockIdx.x * 64;          // 64 consecutive positions
    const int i     = pbase >> 8;               // row index (const per block)
    const int jb    = pbase & 255;              // col base

    if (tid < 128) { lnw_s[tid] = ln_w[tid]; lnb_s[tid] = ln_b[tid]; }

    // load act tile (coalesced: c fastest)
    for (int it = 0; it < 32; ++it) {
        int id = it * 256 + tid;                // 0..8191
        int c = id & 127, m = id >> 7;
        act_s[m][c] = act[(size_t)(pbase + m) * 128 + c];
    }
    __syncthreads();

    // LN reduction: 4 partial sums per position
    {
        int s = tid >> 6, m = tid & 63;
        float a = 0.f, b = 0.f;
        #pragma unroll
        for (int cc = 0; cc < 32; ++cc) {
            float x = act_s[m][s * 32 + cc];
            a += x; b += x * x;
        }
        psum[s][m] = a; psq[s][m] = b;
    }
    __syncthreads();
    if (tid < 64) {
        float a = psum[0][tid] + psum[1][tid] + psum[2][tid] + psum[3][tid];
        float b = psq[0][tid] + psq[1][tid] + psq[2][tid] + psq[3][tid];
        float mu  = a * (1.f / 128.f);
        float var = b * (1.f / 128.f) - mu * mu;
        mu_s[tid] = mu;
        rs_s[tid] = rsqrtf(var + LN_EPS);
    }
    __syncthreads();

    // normalize in place
    for (int it = 0; it < 32; ++it) {
        int id = it * 256 + tid;
        int c = id & 127, m = id >> 7;
        float x = act_s[m][c];
        act_s[m][c] = (x - mu_s[m]) * rs_s[m] * lnw_s[c] + lnb_s[c];
    }
    __syncthreads();

    // pair bias: nb[h, q=i_pos, k=j_pos] = dot(x, w2d[:,h]); store transposed
    {
        int m = tid >> 2, h = tid & 3;
        float acc = 0.f;
        #pragma unroll 4
        for (int c = 0; c < 128; ++c)
            acc += act_s[m][c] * w2d[c * 4 + h];
        int j = jb + m;
        nb_t[h * 65536 + j * 256 + i] = acc;     // [h][k][q]
    }

    // projections: 4 matrices x 2 column-halves
    const int n0 = (tid & 31) * 2;
    const int m0 = (tid >> 5) * 8;
    const float qscale = 0.17677669529663687f;   // 32^-0.5

    for (int ch = 0; ch < 8; ++ch) {
        const int mat = ch >> 1, half = ch & 1;
        const float* W = (mat == 0) ? wq : (mat == 1) ? wk
                       : (mat == 2) ? wv : wg;
        __syncthreads();
        for (int it = 0; it < 8; ++it) {
            int f4 = it * 256 + tid;             // 2048 float4
            int nl4 = f4 & 15, d = f4 >> 4;
            *(float4*)&w_s[d][nl4 * 4] =
                *(const float4*)&W[d * 128 + half * 64 + nl4 * 4];
        }
        __syncthreads();

        float acc[8][2];
        #pragma unroll
        for (int r = 0; r < 8; ++r) { acc[r][0] = 0.f; acc[r][1] = 0.f; }

        #pragma unroll 4
        for (int d = 0; d < 128; ++d) {
            float w0 = w_s[d][n0], w1 = w_s[d][n0 + 1];
            #pragma unroll
            for (int r = 0; r < 8; ++r) {
                float xv = act_s[m0 + r][d];
                acc[r][0] += xv * w0;
                acc[r][1] += xv * w1;
            }
        }

        float* obuf = (mat == 0) ? q_buf : (mat == 1) ? k_buf
                    : (mat == 2) ? v_buf : g_buf;
        #pragma unroll
        for (int r = 0; r < 8; ++r) {
            int jj = jb + m0 + r;
            #pragma unroll
            for (int u = 0; u < 2; ++u) {
                int col = half * 64 + n0 + u;
                int h = col >> 5, c = col & 31;
                float v = acc[r][u];
                if (mat == 0) v *= qscale;
                if (mat == 3) v = 1.f / (1.f + __expf(-(v + bg[col])));
                obuf[(size_t)((i * 4 + h) * 256 + jj) * 32 + c] = v;
            }
        }
    }
}

// ---------------------------------------------------------------------------
// Kernel 2: attention per (row i, head h). grid 1024, block 256 (1 thr = 1 q)
// writes o*g in place over g_buf
// ---------------------------------------------------------------------------
__global__ __launch_bounds__(256) void attn_kernel(
    const float* __restrict__ mask,
    const float* __restrict__ q_buf, const float* __restrict__ k_buf,
    const float* __restrict__ v_buf, float* g_buf,
    const float* __restrict__ nb_t)
{
    __shared__ float k_s[256 * 32];
    __shared__ float v_s[256 * 32];
    __shared__ float bias_s[256];

    const int tid = threadIdx.x;
    const int bid = blockIdx.x;
    const int i = bid >> 2, h = bid & 3;
    const size_t base = (size_t)(i * 4 + h) * 8192;

    for (int it = 0; it < 8; ++it) {
        int f4 = it * 256 + tid;
        ((float4*)k_s)[f4] = ((const float4*)(k_buf + base))[f4];
        ((float4*)v_s)[f4] = ((const float4*)(v_buf + base))[f4];
    }
    bias_s[tid] = 1e9f * (mask[i * 256 + tid] - 1.f);

    float q[32];
    {
        const float4* qp = (const float4*)(q_buf + base + (size_t)tid * 32);
        #pragma unroll
        for (int c4 = 0; c4 < 8; ++c4) {
            float4 t = qp[c4];
            q[c4 * 4 + 0] = t.x; q[c4 * 4 + 1] = t.y;
            q[c4 * 4 + 2] = t.z; q[c4 * 4 + 3] = t.w;
        }
    }
    __syncthreads();

    float m_run = -INFINITY, l = 0.f;
    float o[32];
    #pragma unroll
    for (int c = 0; c < 32; ++c) o[c] = 0.f;

    const float* nbp = nb_t + h * 65536 + tid;   // [h][kk][q=tid]
    float nbv = nbp[0];
    for (int kk = 0; kk < 256; ++kk) {
        float nbn = (kk < 255) ? nbp[(kk + 1) * 256] : 0.f;
        const float* kr = &k_s[kk * 32];
        float dot = 0.f;
        #pragma unroll
        for (int c = 0; c < 32; ++c) dot += q[c] * kr[c];
        float s = dot + bias_s[kk] + nbv;

        float mn   = fmaxf(m_run, s);
        float corr = __expf(m_run - mn);
        float p    = __expf(s - mn);
        l = l * corr + p;
        const float* vr = &v_s[kk * 32];
        #pragma unroll
        for (int c = 0; c < 32; ++c) o[c] = o[c] * corr + p * vr[c];
        m_run = mn;
        nbv = nbn;
    }

    float inv = 1.f / l;
    float* gp = g_buf + base + (size_t)tid * 32;
    #pragma unroll
    for (int c = 0; c < 32; ++c) gp[c] = o[c] * inv * gp[c];
}

// ---------------------------------------------------------------------------
// Kernel 3: output projection. grid 2048 (64 pos x 64-col half), block 256
// ---------------------------------------------------------------------------
__global__ __launch_bounds__(256) void out_kernel(
    const float* __restrict__ g_buf, const float* __restrict__ wo,
    const float* __restrict__ bo, float* __restrict__ out)
{
    __shared__ float og_s[64][128];
    __shared__ float wo_s[128][64];

    const int tid = threadIdx.x;
    const int mt = blockIdx.x >> 1, half = blockIdx.x & 1;
    const int pbase = mt * 64;
    const int i = pbase >> 8, jb = pbase & 255;

    for (int it = 0; it < 8; ++it) {
        int f4 = it * 256 + tid;                 // 2048 float4
        int c4 = f4 & 31, m = f4 >> 5;
        int n = c4 * 4, hh = n >> 5, c = n & 31;
        *(float4*)&og_s[m][n] =
            *(const float4*)&g_buf[(size_t)(((i * 4 + hh) * 256) + jb + m) * 32 + c];
    }
    for (int it = 0; it < 8; ++it) {
        int f4 = it * 256 + tid;
        int nl4 = f4 & 15, d = f4 >> 4;
        *(float4*)&wo_s[d][nl4 * 4] =
            *(const float4*)&wo[d * 128 + half * 64 + nl4 * 4];
    }
    __syncthreads();

    const int n0 = (tid & 31) * 2, m0 = (tid >> 5) * 8;
    float acc[8][2];
    #pragma unroll
    for (int r = 0; r < 8; ++r) { acc[r][0] = 0.f; acc[r][1] = 0.f; }

    #pragma unroll 4
    for (int d = 0; d < 128; ++d) {
        float w0 = wo_s[d][n0], w1 = wo_s[d][n0 + 1];
        #pragma unroll
        for (int r = 0; r < 8; ++r) {
            float xv = og_s[m0 + r][d];
            acc[r][0] += xv * w0;
            acc[r][1] += xv * w1;
        }
    }

    #pragma unroll
    for (int r = 0; r < 8; ++r) {
        int p = pbase + m0 + r;
        int co = half * 64 + n0;
        float2 st;
        st.x = acc[r][0] + bo[co];
        st.y = acc[r][1] + bo[co + 1];
        *(float2*)&out[(size_t)p * 128 + co] = st;
    }
}

// ---------------------------------------------------------------------------
extern "C" void kernel_launch(void* const* d_in, const int* in_sizes, int n_in,
                              void* d_out, int out_size, void* d_ws, size_t ws_size,
                              hipStream_t stream) {
    const float* act  = (const float*)d_in[0];
    const float* mask = (const float*)d_in[1];
    const float* ln_w = (const float*)d_in[2];
    const float* ln_b = (const float*)d_in[3];
    const float* w2d  = (const float*)d_in[4];
    const float* wq   = (const float*)d_in[5];
    const float* wk   = (const float*)d_in[6];
    const float* wv   = (const float*)d_in[7];
    const float* wg   = (const float*)d_in[8];
    const float* bg   = (const float*)d_in[9];
    const float* wo   = (const float*)d_in[10];
    const float* bo   = (const float*)d_in[11];
    float* out = (float*)d_out;

    float* ws    = (float*)d_ws;
    float* q_buf = ws;
    float* k_buf = q_buf + 8388608;
    float* v_buf = k_buf + 8388608;
    float* g_buf = v_buf + 8388608;
    float* nb_t  = g_buf + 8388608;

    proj_kernel<<<1024, 256, 0, stream>>>(act, ln_w, ln_b, w2d, wq, wk, wv, wg,
                                          bg, q_buf, k_buf, v_buf, g_buf, nb_t);
    attn_kernel<<<1024, 256, 0, stream>>>(mask, q_buf, k_buf, v_buf, g_buf, nb_t);
    out_kernel<<<2048, 256, 0, stream>>>(g_buf, wo, bo, out);
}

// Round 2
// 130.784 us; speedup vs baseline: 3.5555x; 3.5555x over previous
//
#include <hip/hip_runtime.h>
#include <hip/hip_bf16.h>
#include <math.h>

#define C_IN   128
#define NSEQ   256
#define LN_EPS 1e-5f
#define LOG2E  1.4426950408889634f

typedef __attribute__((ext_vector_type(8))) short bf16x8;
typedef __attribute__((ext_vector_type(4))) float f32x4;

__device__ __forceinline__ short f2bf(float x) {
    unsigned u = __builtin_bit_cast(unsigned, x);
    u = (u + 0x7FFF + ((u >> 16) & 1)) >> 16;
    return (short)u;
}

// ---------------------------------------------------------------------------
// ws layout (bytes):
//  q_buf  bf16 [65536][128] : 16,777,216
//  k_buf  bf16              : 16,777,216
//  v_buf  bf16              : 16,777,216
//  og_buf bf16              : 16,777,216
//  g_buf  f32  [65536][128] : 33,554,432
//  nb2    f32  [4][65536]   :  1,048,576   ([h][q][k], pre-scaled by log2e)
//  wT     bf16 5*16384+2048 :    167,936   ([mat][col][k]; mat4=wo; +w2d tile)
// ---------------------------------------------------------------------------

// Kernel 0: weight transpose + bf16 convert. 328 blocks x 256.
__global__ __launch_bounds__(256) void prep_kernel(
    const float* __restrict__ wq, const float* __restrict__ wk,
    const float* __restrict__ wv, const float* __restrict__ wg,
    const float* __restrict__ wo, const float* __restrict__ w2d,
    short* __restrict__ wT)
{
    int gid = blockIdx.x * 256 + threadIdx.x;
    if (gid < 5 * 16384) {
        int m = gid >> 14, r = gid & 16383, col = r >> 7, k = r & 127;
        const float* W = (m == 0) ? wq : (m == 1) ? wk : (m == 2) ? wv
                       : (m == 3) ? wg : wo;
        float s = (m == 0) ? (0.17677669529663687f * LOG2E) : 1.0f;
        wT[gid] = f2bf(W[k * 128 + col] * s);
    } else if (gid < 5 * 16384 + 16 * 128) {
        int r = gid - 5 * 16384, col = r >> 7, k = r & 127;
        float v = (col < 4) ? w2d[k * 4 + col] * LOG2E : 0.0f;
        wT[gid] = f2bf(v);
    }
}

// ---------------------------------------------------------------------------
// Kernel 1: LN + projections via MFMA. 1024 blocks (64 positions), 256 thr.
// wave 0 -> wq (+nb tile), wave 1 -> wk, wave 2 -> wv, wave 3 -> wg.
// ---------------------------------------------------------------------------
__global__ __launch_bounds__(256) void proj_kernel(
    const float* __restrict__ act, const float* __restrict__ ln_w,
    const float* __restrict__ ln_b, const float* __restrict__ bg,
    const short* __restrict__ wT,
    short* __restrict__ q_buf, short* __restrict__ k_buf,
    short* __restrict__ v_buf, float* __restrict__ g_buf,
    float* __restrict__ nb2)
{
    __shared__ float psum[4][64], psq[4][64];
    __shared__ float mu_s[64], rs_s[64];
    __shared__ float lnw_s[128], lnb_s[128];

    const int tid = threadIdx.x;
    const int pbase = blockIdx.x * 64;

    if (tid < 128) { lnw_s[tid] = ln_w[tid]; lnb_s[tid] = ln_b[tid]; }

    // LN stats
    {
        int m = tid >> 2, qd = tid & 3;
        const float* row = act + (size_t)(pbase + m) * 128 + qd * 32;
        float a = 0.f, b = 0.f;
        #pragma unroll
        for (int j = 0; j < 8; ++j) {
            float4 t = *(const float4*)(row + j * 4);
            a += t.x + t.y + t.z + t.w;
            b += t.x * t.x + t.y * t.y + t.z * t.z + t.w * t.w;
        }
        psum[qd][m] = a; psq[qd][m] = b;
    }
    __syncthreads();
    if (tid < 64) {
        float a = psum[0][tid] + psum[1][tid] + psum[2][tid] + psum[3][tid];
        float b = psq[0][tid] + psq[1][tid] + psq[2][tid] + psq[3][tid];
        float mu = a * (1.f / 128.f);
        float var = b * (1.f / 128.f) - mu * mu;
        mu_s[tid] = mu; rs_s[tid] = rsqrtf(var + LN_EPS);
    }
    __syncthreads();

    const int w = tid >> 6, l = tid & 63, lr = l & 15, lh = l >> 4;

    // A fragments with LN applied on the fly (bf16)
    bf16x8 af[4][4];
    #pragma unroll
    for (int qt = 0; qt < 4; ++qt) {
        int m = qt * 16 + lr;
        float mu = mu_s[m], rs = rs_s[m];
        const float* rowp = act + (size_t)(pbase + m) * 128 + lh * 8;
        #pragma unroll
        for (int kc = 0; kc < 4; ++kc) {
            float4 a = *(const float4*)(rowp + kc * 32);
            float4 b = *(const float4*)(rowp + kc * 32 + 4);
            int c0 = kc * 32 + lh * 8;
            bf16x8 f;
            f[0] = f2bf((a.x - mu) * rs * lnw_s[c0 + 0] + lnb_s[c0 + 0]);
            f[1] = f2bf((a.y - mu) * rs * lnw_s[c0 + 1] + lnb_s[c0 + 1]);
            f[2] = f2bf((a.z - mu) * rs * lnw_s[c0 + 2] + lnb_s[c0 + 2]);
            f[3] = f2bf((a.w - mu) * rs * lnw_s[c0 + 3] + lnb_s[c0 + 3]);
            f[4] = f2bf((b.x - mu) * rs * lnw_s[c0 + 4] + lnb_s[c0 + 4]);
            f[5] = f2bf((b.y - mu) * rs * lnw_s[c0 + 5] + lnb_s[c0 + 5]);
            f[6] = f2bf((b.z - mu) * rs * lnw_s[c0 + 6] + lnb_s[c0 + 6]);
            f[7] = f2bf((b.w - mu) * rs * lnw_s[c0 + 7] + lnb_s[c0 + 7]);
            af[qt][kc] = f;
        }
    }

    const int nct = (w == 0) ? 9 : 8;
    for (int ct = 0; ct < nct; ++ct) {
        const short* bp = (ct < 8)
            ? (wT + w * 16384 + (ct * 16 + lr) * 128 + lh * 8)
            : (wT + 5 * 16384 + lr * 128 + lh * 8);
        f32x4 z = {0.f, 0.f, 0.f, 0.f};
        f32x4 acc0 = z, acc1 = z, acc2 = z, acc3 = z;
        #pragma unroll
        for (int kc = 0; kc < 4; ++kc) {
            bf16x8 b = *(const bf16x8*)(bp + kc * 32);
            acc0 = __builtin_amdgcn_mfma_f32_16x16x32_bf16(af[0][kc], b, acc0, 0, 0, 0);
            acc1 = __builtin_amdgcn_mfma_f32_16x16x32_bf16(af[1][kc], b, acc1, 0, 0, 0);
            acc2 = __builtin_amdgcn_mfma_f32_16x16x32_bf16(af[2][kc], b, acc2, 0, 0, 0);
            acc3 = __builtin_amdgcn_mfma_f32_16x16x32_bf16(af[3][kc], b, acc3, 0, 0, 0);
        }
        f32x4 acc[4] = {acc0, acc1, acc2, acc3};
        if (ct < 8) {
            int col = ct * 16 + lr;
            if (w == 3) {
                float bgv = bg[col];
                #pragma unroll
                for (int qt = 0; qt < 4; ++qt)
                    #pragma unroll
                    for (int r = 0; r < 4; ++r) {
                        float v = acc[qt][r] + bgv;
                        v = 1.f / (1.f + exp2f(-v * LOG2E));
                        g_buf[(size_t)(pbase + qt * 16 + lh * 4 + r) * 128 + col] = v;
                    }
            } else {
                short* obuf = (w == 0) ? q_buf : (w == 1) ? k_buf : v_buf;
                #pragma unroll
                for (int qt = 0; qt < 4; ++qt)
                    #pragma unroll
                    for (int r = 0; r < 4; ++r)
                        obuf[(size_t)(pbase + qt * 16 + lh * 4 + r) * 128 + col] =
                            f2bf(acc[qt][r]);
            }
        } else {
            int col = lr;  // 0..15; only 0..3 are real heads
            if (col < 4) {
                #pragma unroll
                for (int qt = 0; qt < 4; ++qt)
                    #pragma unroll
                    for (int r = 0; r < 4; ++r)
                        nb2[(size_t)col * 65536 + pbase + qt * 16 + lh * 4 + r] =
                            acc[qt][r];
            }
        }
    }
}

// ---------------------------------------------------------------------------
// Kernel 2: attention, MFMA, exp2-no-max softmax. 1024 blocks (i,h), 256 thr.
// Each wave owns 64 queries.
// ---------------------------------------------------------------------------
__global__ __launch_bounds__(256) void attn_kernel(
    const float* __restrict__ mask,
    const short* __restrict__ q_buf, const short* __restrict__ k_buf,
    const short* __restrict__ v_buf, const float* __restrict__ g_buf,
    const float* __restrict__ nb2, short* __restrict__ og_buf)
{
    __shared__ short k_s[256 * 40];      // [key][c], pitch 40
    __shared__ short vt_s[32 * 264];     // [c][key], pitch 264
    __shared__ short p_s[4][64 * 40];    // per-wave P tile, pitch 40
    __shared__ float bias_s[256];

    const int tid = threadIdx.x, bid = blockIdx.x;
    const int i = bid >> 2, h = bid & 3;
    const size_t pb = (size_t)i * 256 * 128 + h * 32;   // element offset

    // stage K, V^T, bias
    {
        const short* kp = k_buf + pb + (size_t)tid * 128;
        const short* vp = v_buf + pb + (size_t)tid * 128;
        bf16x8 kv[4], vv[4];
        #pragma unroll
        for (int j = 0; j < 4; ++j) kv[j] = *(const bf16x8*)(kp + j * 8);
        #pragma unroll
        for (int j = 0; j < 4; ++j) vv[j] = *(const bf16x8*)(vp + j * 8);
        #pragma unroll
        for (int j = 0; j < 4; ++j) *(bf16x8*)&k_s[tid * 40 + j * 8] = kv[j];
        #pragma unroll
        for (int j = 0; j < 4; ++j)
            #pragma unroll
            for (int e = 0; e < 8; ++e)
                vt_s[(j * 8 + e) * 264 + tid] = vv[j][e];
        bias_s[tid] = 1e9f * (mask[i * 256 + tid] - 1.f) * LOG2E;
    }

    const int w = tid >> 6, l = tid & 63, lr = l & 15, lh = l >> 4;
    const int qbase = w * 64;

    bf16x8 qf[4];
    #pragma unroll
    for (int qt = 0; qt < 4; ++qt)
        qf[qt] = *(const bf16x8*)(q_buf + pb +
                    (size_t)(qbase + qt * 16 + lr) * 128 + lh * 8);
    __syncthreads();

    f32x4 z = {0.f, 0.f, 0.f, 0.f};
    f32x4 o[4][2];
    float lsum[4][4];
    #pragma unroll
    for (int qt = 0; qt < 4; ++qt) {
        o[qt][0] = z; o[qt][1] = z;
        #pragma unroll
        for (int r = 0; r < 4; ++r) lsum[qt][r] = 0.f;
    }
    short* pw = &p_s[w][0];

    for (int kk = 0; kk < 256; kk += 32) {
        // S = Q K^T (log2 domain, scales pre-folded)
        bf16x8 bk0 = *(const bf16x8*)&k_s[(kk + lr) * 40 + lh * 8];
        bf16x8 bk1 = *(const bf16x8*)&k_s[(kk + 16 + lr) * 40 + lh * 8];
        f32x4 s[4][2];
        #pragma unroll
        for (int qt = 0; qt < 4; ++qt) {
            s[qt][0] = __builtin_amdgcn_mfma_f32_16x16x32_bf16(qf[qt], bk0, z, 0, 0, 0);
            s[qt][1] = __builtin_amdgcn_mfma_f32_16x16x32_bf16(qf[qt], bk1, z, 0, 0, 0);
        }
        float b0 = bias_s[kk + lr], b1 = bias_s[kk + 16 + lr];
        #pragma unroll
        for (int qt = 0; qt < 4; ++qt) {
            int q = qbase + qt * 16 + lh * 4;
            const float* nbp = nb2 + (size_t)h * 65536 + (size_t)q * 256 + kk + lr;
            #pragma unroll
            for (int r = 0; r < 4; ++r) {
                float n0 = nbp[r * 256], n1 = nbp[r * 256 + 16];
                float p0 = exp2f(s[qt][0][r] + b0 + n0);
                float p1 = exp2f(s[qt][1][r] + b1 + n1);
                lsum[qt][r] += p0 + p1;
                pw[(qt * 16 + lh * 4 + r) * 40 + lr]      = f2bf(p0);
                pw[(qt * 16 + lh * 4 + r) * 40 + 16 + lr] = f2bf(p1);
            }
        }
        __syncthreads();
        // O += P V
        bf16x8 bv0 = *(const bf16x8*)&vt_s[lr * 264 + kk + lh * 8];
        bf16x8 bv1 = *(const bf16x8*)&vt_s[(16 + lr) * 264 + kk + lh * 8];
        #pragma unroll
        for (int qt = 0; qt < 4; ++qt) {
            bf16x8 ap = *(const bf16x8*)&pw[(qt * 16 + lr) * 40 + lh * 8];
            o[qt][0] = __builtin_amdgcn_mfma_f32_16x16x32_bf16(ap, bv0, o[qt][0], 0, 0, 0);
            o[qt][1] = __builtin_amdgcn_mfma_f32_16x16x32_bf16(ap, bv1, o[qt][1], 0, 0, 0);
        }
        __syncthreads();
    }

    // row sums across the 16 key-lanes
    #pragma unroll
    for (int qt = 0; qt < 4; ++qt)
        #pragma unroll
        for (int r = 0; r < 4; ++r) {
            float v = lsum[qt][r];
            v += __shfl_xor(v, 1); v += __shfl_xor(v, 2);
            v += __shfl_xor(v, 4); v += __shfl_xor(v, 8);
            lsum[qt][r] = 1.f / v;
        }

    // og = (O / l) * g, bf16
    #pragma unroll
    for (int qt = 0; qt < 4; ++qt)
        #pragma unroll
        for (int ct = 0; ct < 2; ++ct) {
            int c = ct * 16 + lr;
            #pragma unroll
            for (int r = 0; r < 4; ++r) {
                int q = qbase + qt * 16 + lh * 4 + r;
                size_t idx = pb + (size_t)q * 128 + c;
                float gv = g_buf[idx];
                og_buf[idx] = f2bf(o[qt][ct][r] * lsum[qt][r] * gv);
            }
        }
}

// ---------------------------------------------------------------------------
// Kernel 3: output projection via MFMA. 1024 blocks (64 pos), 256 thr.
// wave w handles output cols [w*32, w*32+32).
// ---------------------------------------------------------------------------
__global__ __launch_bounds__(256) void out_kernel(
    const short* __restrict__ og_buf, const short* __restrict__ wT,
    const float* __restrict__ bo, float* __restrict__ out)
{
    const int tid = threadIdx.x;
    const int pbase = blockIdx.x * 64;
    const int w = tid >> 6, l = tid & 63, lr = l & 15, lh = l >> 4;

    bf16x8 af[4][4];
    #pragma unroll
    for (int qt = 0; qt < 4; ++qt) {
        const short* rp = og_buf + (size_t)(pbase + qt * 16 + lr) * 128 + lh * 8;
        #pragma unroll
        for (int kc = 0; kc < 4; ++kc) af[qt][kc] = *(const bf16x8*)(rp + kc * 32);
    }
    const short* wo_t = wT + 4 * 16384;
    f32x4 z = {0.f, 0.f, 0.f, 0.f};
    #pragma unroll
    for (int ct = 0; ct < 2; ++ct) {
        int col = w * 32 + ct * 16 + lr;
        f32x4 acc0 = z, acc1 = z, acc2 = z, acc3 = z;
        #pragma unroll
        for (int kc = 0; kc < 4; ++kc) {
            bf16x8 b = *(const bf16x8*)(wo_t + col * 128 + kc * 32 + lh * 8);
            acc0 = __builtin_amdgcn_mfma_f32_16x16x32_bf16(af[0][kc], b, acc0, 0, 0, 0);
            acc1 = __builtin_amdgcn_mfma_f32_16x16x32_bf16(af[1][kc], b, acc1, 0, 0, 0);
            acc2 = __builtin_amdgcn_mfma_f32_16x16x32_bf16(af[2][kc], b, acc2, 0, 0, 0);
            acc3 = __builtin_amdgcn_mfma_f32_16x16x32_bf16(af[3][kc], b, acc3, 0, 0, 0);
        }
        f32x4 acc[4] = {acc0, acc1, acc2, acc3};
        float bov = bo[col];
        #pragma unroll
        for (int qt = 0; qt < 4; ++qt)
            #pragma unroll
            for (int r = 0; r < 4; ++r)
                out[(size_t)(pbase + qt * 16 + lh * 4 + r) * 128 + col] =
                    acc[qt][r] + bov;
    }
}

// ---------------------------------------------------------------------------
extern "C" void kernel_launch(void* const* d_in, const int* in_sizes, int n_in,
                              void* d_out, int out_size, void* d_ws, size_t ws_size,
                              hipStream_t stream) {
    const float* act  = (const float*)d_in[0];
    const float* mask = (const float*)d_in[1];
    const float* ln_w = (const float*)d_in[2];
    const float* ln_b = (const float*)d_in[3];
    const float* w2d  = (const float*)d_in[4];
    const float* wq   = (const float*)d_in[5];
    const float* wk   = (const float*)d_in[6];
    const float* wv   = (const float*)d_in[7];
    const float* wg   = (const float*)d_in[8];
    const float* bg   = (const float*)d_in[9];
    const float* wo   = (const float*)d_in[10];
    const float* bo   = (const float*)d_in[11];
    float* out = (float*)d_out;

    char* ws = (char*)d_ws;
    short* q_buf  = (short*)(ws);
    short* k_buf  = (short*)(ws + 16777216);
    short* v_buf  = (short*)(ws + 2 * 16777216);
    short* og_buf = (short*)(ws + 3 * 16777216);
    float* g_buf  = (float*)(ws + 4 * 16777216);
    float* nb2    = (float*)(ws + 4 * 16777216 + 33554432);
    short* wT     = (short*)(ws + 4 * 16777216 + 33554432 + 1048576);

    prep_kernel<<<328, 256, 0, stream>>>(wq, wk, wv, wg, wo, w2d, wT);
    proj_kernel<<<1024, 256, 0, stream>>>(act, ln_w, ln_b, bg, wT,
                                          q_buf, k_buf, v_buf, g_buf, nb2);
    attn_kernel<<<1024, 256, 0, stream>>>(mask, q_buf, k_buf, v_buf, g_buf,
                                          nb2, og_buf);
    out_kernel<<<1024, 256, 0, stream>>>(og_buf, wT, bo, out);
}